// Round 8
// baseline (130.215 us; speedup 1.0000x reference)
//
#include <hip/hip_runtime.h>

// CirculantSSMLayer on MI355X.
// Pipeline: stats(+weight-prep) -> gemm1 (LN fused into A-staging, Wa|WB fused)
//           -> packed real radix-4 FFT256 -> per-(b,k) scan over T
//           -> packed inverse radix-4 FFT -> bf16 MFMA GEMM + epilogue.
// R8: LN fused into gemm1 A-staging (kills xn roundtrip; stats precomputed);
//     gemm2 epilogue with batched xres loads + hoisted bias/dskip.

typedef unsigned short ushort_t;
typedef short s16x8 __attribute__((ext_vector_type(8)));
typedef float f32x4 __attribute__((ext_vector_type(4)));
typedef _Float16 f16x8 __attribute__((ext_vector_type(8)));
typedef _Float16 f16x2 __attribute__((ext_vector_type(2)));

#define B_ 4
#define T_ 4096
#define D_ 1024
#define N_ 256
#define KB_ 129
#define M_ (B_*T_)

// LDS bank swizzle for float2 arrays: XOR bits 4-5 into bits 1-2 (involution).
#define SWZ(i) ((i) ^ (((i) >> 3) & 6))
// base-4 digit reversal of an 8-bit index (radix-4 FFT input scramble)
#define DR4(n) ((((n) & 3) << 6) | (((n) & 12) << 2) | (((n) & 48) >> 2) | (((n) >> 6) & 3))

__device__ __forceinline__ ushort_t f2bf(float f) {
  unsigned u = __float_as_uint(f);
  u = (u + 0x7FFFu + ((u >> 16) & 1u)) >> 16;
  return (ushort_t)u;
}
__device__ __forceinline__ float2 cmul(float2 a, float2 b) {
  return make_float2(a.x*b.x - a.y*b.y, a.x*b.y + a.y*b.x);
}
__device__ __forceinline__ float fast_tanh(float x) {
  return 1.f - 2.f / (__expf(2.f * x) + 1.f);
}

typedef const __attribute__((address_space(1))) unsigned glb_u32;
typedef __attribute__((address_space(3))) unsigned lds_u32;
__device__ __forceinline__ void gload16(const void* g, void* l) {
  __builtin_amdgcn_global_load_lds((glb_u32*)g, (lds_u32*)l, 16, 0, 0);
}

// ---------------- LN stats (blocks 0..4095) + weight f32->bf16 (4096..4863) ----------
__global__ __launch_bounds__(256) void stats_prep_kernel(const float* __restrict__ x,
    float2* __restrict__ stats,
    const float* __restrict__ Wa, const float* __restrict__ WB,
    const float* __restrict__ WC, ushort_t* __restrict__ Wab,
    ushort_t* __restrict__ WCb) {
  int tid = threadIdx.x;
  if (blockIdx.x >= 4096) {
    int i4 = ((blockIdx.x - 4096) * 256 + tid) * 4;
    float4 v;
    ushort_t* dst;
    if (i4 < 262144)        { v = *(const float4*)(Wa + i4);          dst = Wab + i4; }
    else if (i4 < 524288)   { v = *(const float4*)(WB + i4 - 262144); dst = Wab + i4; }
    else                    { v = *(const float4*)(WC + i4 - 524288); dst = WCb + i4 - 524288; }
    ushort4 o;
    o.x = f2bf(v.x); o.y = f2bf(v.y); o.z = f2bf(v.z); o.w = f2bf(v.w);
    *(ushort4*)dst = o;
    return;
  }
  int lane = tid & 63, wv = tid >> 6;
  int row = blockIdx.x * 4 + wv;
  const float4* xr = (const float4*)(x + (size_t)row * D_);
  float s = 0.f, sq = 0.f;
  #pragma unroll
  for (int j = 0; j < 4; ++j) {
    float4 v = xr[lane + 64 * j];
    s  += v.x + v.y + v.z + v.w;
    sq += v.x*v.x + v.y*v.y + v.z*v.z + v.w*v.w;
  }
  #pragma unroll
  for (int off = 32; off >= 1; off >>= 1) {
    s  += __shfl_xor(s, off);
    sq += __shfl_xor(sq, off);
  }
  if (lane == 0) {
    float mu  = s * (1.0f / D_);
    float var = sq * (1.0f / D_) - mu * mu;
    stats[row] = make_float2(mu, rsqrtf(var + 1e-5f));
  }
}

// ---------------- gemm1 with fused LN: au[m][n] = sum_k LN(x)[m][k]*Wab[n][k] ------
// BM=128 x BN=64, BK=64, 4 waves (2x2), 16x16x32 MFMA. A: reg-staged from x f32,
// normalized via precomputed stats, bf16-cast, written to XOR-swizzled LDS slots
// (slot = g ^ (r&7), matching the frag-read swizzle). B: gload16, pre-swizzled src.
__global__ __launch_bounds__(256) void gemm1_ln(
    const float* __restrict__ x, const float2* __restrict__ stats,
    const float* __restrict__ lnw, const float* __restrict__ lnb,
    const ushort_t* __restrict__ B, _Float16* __restrict__ C) {
  constexpr int NF = 2;                 // BN=64
  __shared__ ushort_t Alds[128 * 64];
  __shared__ ushort_t Blds[64 * 64];
  int bid = blockIdx.x;
  int cpx = gridDim.x >> 3;
  bid = (bid & 7) * cpx + (bid >> 3);
  int mt = bid >> 3, nt = bid & 7;
  int m0 = mt * 128, n0 = nt * 64;
  int tid = threadIdx.x;
  int lane = tid & 63, wid = tid >> 6;
  int wm = wid >> 1, wn = wid & 1;

  // B staging (global_load_lds, pre-swizzled source granule)
  int lr8 = lane >> 3;
  int gd  = (lane & 7) ^ lr8;
  const ushort_t* gB = B + (size_t)(n0 + wid * 16 + lr8) * D_ + gd * 8;
  ushort_t* lB = &Blds[(wid * 16) * 64];

  // A fused-LN staging: thread (rsub = tid>>4, l16 = tid&15) covers rows
  // rsub+16*it (it 0..8) x float4 at col l16*4. slot is it-invariant.
  int rsub = tid >> 4, l16 = tid & 15;
  int slotA = ((l16 >> 1) ^ (rsub & 7)) * 8 + (l16 & 1) * 4;
  float2 st[8];
  #pragma unroll
  for (int it = 0; it < 8; ++it) st[it] = stats[m0 + rsub + it * 16];

  f32x4 acc[4][NF] = {};
  int rbase = lane & 15;
  int rb7 = lane & 7;
  int gk0 = lane >> 4;

  for (int k0 = 0; k0 < D_; k0 += 64) {
    __syncthreads();
    float4 wv = *(const float4*)(lnw + k0 + l16 * 4);
    float4 bv = *(const float4*)(lnb + k0 + l16 * 4);
    #pragma unroll
    for (int it = 0; it < 8; ++it) {
      int r = rsub + it * 16;
      float4 xv = *(const float4*)(x + (size_t)(m0 + r) * D_ + k0 + l16 * 4);
      float mu = st[it].x, rs = st[it].y;
      ushort4 o;
      o.x = f2bf((xv.x - mu) * rs * wv.x + bv.x);
      o.y = f2bf((xv.y - mu) * rs * wv.y + bv.y);
      o.z = f2bf((xv.z - mu) * rs * wv.z + bv.z);
      o.w = f2bf((xv.w - mu) * rs * wv.w + bv.w);
      *(ushort4*)(&Alds[r * 64 + slotA]) = o;
    }
    #pragma unroll
    for (int c = 0; c < 2; ++c)
      gload16(gB + (size_t)(c * 8) * D_ + k0, lB + c * 8 * 64);
    __syncthreads();
    #pragma unroll
    for (int kk = 0; kk < 2; ++kk) {
      int sl = ((gk0 + kk * 4) ^ rb7) * 8;
      s16x8 af[4], bf[NF];
      #pragma unroll
      for (int i = 0; i < 4; ++i)
        af[i] = *reinterpret_cast<const s16x8*>(&Alds[(wm * 64 + i * 16 + rbase) * 64 + sl]);
      #pragma unroll
      for (int j = 0; j < NF; ++j)
        bf[j] = *reinterpret_cast<const s16x8*>(&Blds[(wn * 32 + j * 16 + rbase) * 64 + sl]);
      #pragma unroll
      for (int i = 0; i < 4; ++i)
        #pragma unroll
        for (int j = 0; j < NF; ++j)
          acc[i][j] = __builtin_amdgcn_mfma_f32_16x16x32_bf16(af[i], bf[j], acc[i][j], 0, 0, 0);
    }
  }

  int r0 = (lane >> 4) * 4, cc = lane & 15;
  #pragma unroll
  for (int i = 0; i < 4; ++i)
    #pragma unroll
    for (int j = 0; j < NF; ++j) {
      int col = n0 + wn * 32 + j * 16 + cc;
      #pragma unroll
      for (int r = 0; r < 4; ++r) {
        int row = m0 + wm * 64 + i * 16 + r0 + r;
        C[(size_t)row * 512 + col] = (_Float16)acc[i][j][r];
      }
    }
}

// ---------------- gemm2: out[m][n] = sum_k hb[m][k]*WCb[n][k] + bias + dskip*xres ---
// BM=128 x BN=128, BK=64, 4 waves (2x2), gload16 both operands, granule swizzle.
__global__ __launch_bounds__(256) void gemm2_epi(
    const ushort_t* __restrict__ A, const ushort_t* __restrict__ B,
    float* __restrict__ C,
    const float* __restrict__ bias, const float* __restrict__ dskip,
    const float* __restrict__ xres) {
  constexpr int BN = 128, NF = 4;
  __shared__ ushort_t Alds[128 * 64];
  __shared__ ushort_t Blds[BN * 64];
  int bid = blockIdx.x;
  int cpx = gridDim.x >> 3;
  bid = (bid & 7) * cpx + (bid >> 3);
  int mt = bid >> 3, nt = bid & 7;
  int m0 = mt * 128, n0 = nt * BN;
  int tid = threadIdx.x;
  int lane = tid & 63, wid = tid >> 6;
  int wm = wid >> 1, wn = wid & 1;

  int lr8 = lane >> 3;
  int gd  = (lane & 7) ^ lr8;
  const ushort_t* gA = A + (size_t)(m0 + wid * 32 + lr8) * N_ + gd * 8;
  ushort_t* lA = &Alds[(wid * 32) * 64];
  const ushort_t* gB = B + (size_t)(n0 + wid * 32 + lr8) * N_ + gd * 8;
  ushort_t* lB = &Blds[(wid * 32) * 64];

  f32x4 acc[4][NF] = {};
  int rbase = lane & 15;
  int rb7 = lane & 7;
  int gk0 = lane >> 4;

  for (int k0 = 0; k0 < N_; k0 += 64) {
    __syncthreads();
    #pragma unroll
    for (int c = 0; c < 4; ++c) {
      gload16(gA + (size_t)(c * 8) * N_ + k0, lA + c * 8 * 64);
      gload16(gB + (size_t)(c * 8) * N_ + k0, lB + c * 8 * 64);
    }
    __syncthreads();
    #pragma unroll
    for (int kk = 0; kk < 2; ++kk) {
      int sl = ((gk0 + kk * 4) ^ rb7) * 8;
      s16x8 af[4], bf[NF];
      #pragma unroll
      for (int i = 0; i < 4; ++i)
        af[i] = *reinterpret_cast<const s16x8*>(&Alds[(wm * 64 + i * 16 + rbase) * 64 + sl]);
      #pragma unroll
      for (int j = 0; j < NF; ++j)
        bf[j] = *reinterpret_cast<const s16x8*>(&Blds[(wn * 64 + j * 16 + rbase) * 64 + sl]);
      #pragma unroll
      for (int i = 0; i < 4; ++i)
        #pragma unroll
        for (int j = 0; j < NF; ++j)
          acc[i][j] = __builtin_amdgcn_mfma_f32_16x16x32_bf16(af[i], bf[j], acc[i][j], 0, 0, 0);
    }
  }

  int r0 = (lane >> 4) * 4, cc = lane & 15;
  // hoist per-column epilogue scalars
  float bcol[NF], dcol[NF];
  #pragma unroll
  for (int j = 0; j < NF; ++j) {
    int col = n0 + wn * 64 + j * 16 + cc;
    bcol[j] = bias[col];
    dcol[j] = dskip[col];
  }
  #pragma unroll
  for (int i = 0; i < 4; ++i) {
    // batch all 16 xres loads for this row-group before use
    float xr[NF][4];
    #pragma unroll
    for (int j = 0; j < NF; ++j)
      #pragma unroll
      for (int r = 0; r < 4; ++r)
        xr[j][r] = xres[(size_t)(m0 + wm * 64 + i * 16 + r0 + r) * D_ +
                        n0 + wn * 64 + j * 16 + cc];
    #pragma unroll
    for (int j = 0; j < NF; ++j) {
      int col = n0 + wn * 64 + j * 16 + cc;
      #pragma unroll
      for (int r = 0; r < 4; ++r) {
        int row = m0 + wm * 64 + i * 16 + r0 + r;
        C[(size_t)row * D_ + col] = acc[i][j][r] + bcol[j] + dcol[j] * xr[j][r];
      }
    }
  }
}

// ---------------- forward: bias+tanh+gate, packed radix-4 FFT256 ----------------
__global__ __launch_bounds__(512) void fft_fwd(const _Float16* __restrict__ au,
    const float* __restrict__ ba, const float* __restrict__ bu,
    const float* __restrict__ lg, _Float16* __restrict__ ah, _Float16* __restrict__ uh) {
  __shared__ float2 Z[8][256];
  __shared__ float2 Tw[256];
  int tid = threadIdx.x;
  int m0 = blockIdx.x * 8;
  int tg = tid >> 6, lane = tid & 63;
  if (tid < 256) {
    float sn, cs;
    __sincosf(-6.2831853071795864f / 256.f * (float)tid, &sn, &cs);
    Tw[tid] = make_float2(cs, sn);
  }
  float gamma = 1.f / (1.f + __expf(-lg[0]));
  const _Float16* row = au + (size_t)(m0 + tg) * (2 * N_);
  #pragma unroll
  for (int j = 0; j < 4; ++j) {
    int n = lane + 64 * j;
    float a = gamma * fast_tanh((float)row[n] + ba[n]);
    float u = (float)row[N_ + n] + bu[n];
    Z[tg][SWZ(DR4(n))] = make_float2(a, u);
  }
  __syncthreads();
  #pragma unroll
  for (int ls = 0; ls < 4; ++ls) {
    const int Q = 1 << (2 * ls);
    const int step = 64 >> (2 * ls);
    int j = lane & (Q - 1);
    int g = lane >> (2 * ls);
    int base = g * (4 * Q) + j;
    float2 a0 = Z[tg][SWZ(base)];
    float2 a1 = Z[tg][SWZ(base + Q)];
    float2 a2 = Z[tg][SWZ(base + 2 * Q)];
    float2 a3 = Z[tg][SWZ(base + 3 * Q)];
    if (ls > 0) {
      int e = j * step;
      a1 = cmul(a1, Tw[e]);
      a2 = cmul(a2, Tw[2 * e]);
      a3 = cmul(a3, Tw[3 * e]);
    }
    float2 t0 = make_float2(a0.x + a2.x, a0.y + a2.y);
    float2 t1 = make_float2(a0.x - a2.x, a0.y - a2.y);
    float2 t2 = make_float2(a1.x + a3.x, a1.y + a3.y);
    float2 d  = make_float2(a1.x - a3.x, a1.y - a3.y);
    float2 t3 = make_float2(d.y, -d.x);
    Z[tg][SWZ(base)]         = make_float2(t0.x + t2.x, t0.y + t2.y);
    Z[tg][SWZ(base + Q)]     = make_float2(t1.x + t3.x, t1.y + t3.y);
    Z[tg][SWZ(base + 2 * Q)] = make_float2(t0.x - t2.x, t0.y - t2.y);
    Z[tg][SWZ(base + 3 * Q)] = make_float2(t1.x - t3.x, t1.y - t3.y);
  }
  __syncthreads();
  int b = m0 >> 12, tb = m0 & (T_ - 1);
  #pragma unroll
  for (int p = 0; p < 3; ++p) {
    int k = (tid >> 3) + p * 64;
    int tl = tid & 7;
    if (k <= 128) {
      float2 zk = Z[tl][SWZ(k)];
      float2 zn = Z[tl][SWZ((256 - k) & 255)];
      float2 Af = make_float2(0.5f * (zk.x + zn.x), 0.5f * (zk.y - zn.y));
      float2 Uf = make_float2(0.5f * (zk.y + zn.y), -0.5f * (zk.x - zn.x));
      float mag = fmaxf(sqrtf(Af.x * Af.x + Af.y * Af.y), 1e-8f);
      float scl = 1.f / (1.f + __expf(-2.f * (1.f - mag)));
      Af.x *= scl; Af.y *= scl;
      size_t off2 = (((size_t)(b * KB_ + k)) * T_ + tb + tl) * 2;
      f16x2 av; av[0] = (_Float16)Af.x; av[1] = (_Float16)Af.y;
      f16x2 uv; uv[0] = (_Float16)Uf.x; uv[1] = (_Float16)Uf.y;
      *(f16x2*)(ah + off2) = av;
      *(f16x2*)(uh + off2) = uv;
    }
  }
}

// ---------------- time scan: h_t = a_t*h_{t-1} + u_t per (b,k) chain ----------------
__global__ __launch_bounds__(512) void scan_kernel(const _Float16* __restrict__ ah,
                                                   _Float16* __restrict__ uh) {
  __shared__ float4 wagg[8];
  int tid = threadIdx.x;
  int lane = tid & 63, wv = tid >> 6;
  size_t base = (size_t)blockIdx.x * T_ * 2;
  const f16x8* a8 = (const f16x8*)(ah + base);
  f16x8* u8 = (f16x8*)(uh + base);
  f16x8 Av[2], Uv[2];
  #pragma unroll
  for (int q = 0; q < 2; ++q) { Av[q] = a8[tid * 2 + q]; Uv[q] = u8[tid * 2 + q]; }
  float2 La[8], Lb[8];
  float2 ra = make_float2(1.f, 0.f), rb = make_float2(0.f, 0.f);
  #pragma unroll
  for (int e = 0; e < 8; ++e) {
    const int q = e >> 2, i = (e & 3) * 2;
    float2 a = make_float2((float)Av[q][i], (float)Av[q][i + 1]);
    float2 u = make_float2((float)Uv[q][i], (float)Uv[q][i + 1]);
    float2 t = cmul(a, rb);
    rb = make_float2(t.x + u.x, t.y + u.y);
    ra = cmul(ra, a);
    La[e] = ra; Lb[e] = rb;
  }
  #pragma unroll
  for (int off = 1; off < 64; off <<= 1) {
    float ax = __shfl_up(ra.x, off, 64), ay = __shfl_up(ra.y, off, 64);
    float bx = __shfl_up(rb.x, off, 64), by = __shfl_up(rb.y, off, 64);
    if (lane >= off) {
      float2 Ap = make_float2(ax, ay), Bp = make_float2(bx, by);
      float2 nB = cmul(ra, Bp);
      nB.x += rb.x; nB.y += rb.y;
      ra = cmul(Ap, ra);
      rb = nB;
    }
  }
  if (lane == 63) wagg[wv] = make_float4(ra.x, ra.y, rb.x, rb.y);
  __syncthreads();
  float2 Bw = make_float2(0.f, 0.f);
  for (int w0 = 0; w0 < wv; ++w0) {
    float4 g = wagg[w0];
    float2 gA = make_float2(g.x, g.y), gB = make_float2(g.z, g.w);
    Bw = cmul(gA, Bw);
    Bw.x += gB.x; Bw.y += gB.y;
  }
  float ax = __shfl_up(ra.x, 1, 64), ay = __shfl_up(ra.y, 1, 64);
  float bx = __shfl_up(rb.x, 1, 64), by = __shfl_up(rb.y, 1, 64);
  float2 Ae, Be;
  if (lane == 0) { Ae = make_float2(1.f, 0.f); Be = make_float2(0.f, 0.f); }
  else           { Ae = make_float2(ax, ay);   Be = make_float2(bx, by);   }
  float2 Pb = cmul(Ae, Bw);
  Pb.x += Be.x; Pb.y += Be.y;
  #pragma unroll
  for (int q = 0; q < 2; ++q) {
    f16x8 o;
    #pragma unroll
    for (int e2 = 0; e2 < 4; ++e2) {
      const int e = q * 4 + e2;
      float2 h = cmul(La[e], Pb);
      h.x += Lb[e].x; h.y += Lb[e].y;
      o[e2 * 2]     = (_Float16)h.x;
      o[e2 * 2 + 1] = (_Float16)h.y;
    }
    u8[tid * 2 + q] = o;
  }
}

// ---------------- inverse radix-4 FFT: 2 real rows per complex transform -> h bf16 ----
__global__ __launch_bounds__(256) void ifft_kernel(const _Float16* __restrict__ hh,
                                                   ushort_t* __restrict__ hb) {
  __shared__ float2 Hraw[8][132];
  __shared__ float2 Wz[4][256];
  __shared__ float2 Tw[256];
  int tid = threadIdx.x;
  int m0 = blockIdx.x * 8;
  int b = m0 >> 12, tb = m0 & (T_ - 1);
  {
    float sn, cs;
    __sincosf(6.2831853071795864f / 256.f * (float)tid, &sn, &cs);
    Tw[tid] = make_float2(cs, sn);
  }
  #pragma unroll
  for (int p = 0; p < 5; ++p) {
    int k = p * 32 + (tid >> 3), tl = tid & 7;
    if (k <= 128) {
      f16x2 hv = *(const f16x2*)(hh + (((size_t)(b * KB_ + k)) * T_ + tb + tl) * 2);
      Hraw[tl][k] = make_float2((float)hv[0], (float)hv[1]);
    }
  }
  __syncthreads();
  #pragma unroll
  for (int p = 0; p < 3; ++p) {
    int idx = p * 256 + tid;
    if (idx < 516) {
      int k = idx >> 2, pr = idx & 3;
      float2 h1 = Hraw[2 * pr][k], h2 = Hraw[2 * pr + 1][k];
      Wz[pr][SWZ(DR4(k))] = make_float2(h1.x - h2.y, h1.y + h2.x);
      if (k >= 1 && k <= 127)
        Wz[pr][SWZ(DR4(256 - k))] = make_float2(h1.x + h2.y, h2.x - h1.y);
    }
  }
  __syncthreads();
  int pr = tid >> 6, lane = tid & 63;
  #pragma unroll
  for (int ls = 0; ls < 4; ++ls) {
    const int Q = 1 << (2 * ls);
    const int step = 64 >> (2 * ls);
    int j = lane & (Q - 1);
    int g = lane >> (2 * ls);
    int base = g * (4 * Q) + j;
    float2 a0 = Wz[pr][SWZ(base)];
    float2 a1 = Wz[pr][SWZ(base + Q)];
    float2 a2 = Wz[pr][SWZ(base + 2 * Q)];
    float2 a3 = Wz[pr][SWZ(base + 3 * Q)];
    if (ls > 0) {
      int e = j * step;
      a1 = cmul(a1, Tw[e]);
      a2 = cmul(a2, Tw[2 * e]);
      a3 = cmul(a3, Tw[3 * e]);
    }
    float2 t0 = make_float2(a0.x + a2.x, a0.y + a2.y);
    float2 t1 = make_float2(a0.x - a2.x, a0.y - a2.y);
    float2 t2 = make_float2(a1.x + a3.x, a1.y + a3.y);
    float2 d  = make_float2(a1.x - a3.x, a1.y - a3.y);
    float2 t3 = make_float2(-d.y, d.x);
    Wz[pr][SWZ(base)]         = make_float2(t0.x + t2.x, t0.y + t2.y);
    Wz[pr][SWZ(base + Q)]     = make_float2(t1.x + t3.x, t1.y + t3.y);
    Wz[pr][SWZ(base + 2 * Q)] = make_float2(t0.x - t2.x, t0.y - t2.y);
    Wz[pr][SWZ(base + 3 * Q)] = make_float2(t1.x - t3.x, t1.y - t3.y);
  }
  const float inv = 1.f / 256.f;
  #pragma unroll
  for (int j = 0; j < 4; ++j) {
    int n = lane + 64 * j;
    float2 wv = Wz[pr][SWZ(n)];
    hb[(size_t)(m0 + 2 * pr) * N_ + n]     = f2bf(wv.x * inv);
    hb[(size_t)(m0 + 2 * pr + 1) * N_ + n] = f2bf(wv.y * inv);
  }
}

// ---------------- launch ----------------
extern "C" void kernel_launch(void* const* d_in, const int* in_sizes, int n_in,
                              void* d_out, int out_size, void* d_ws, size_t ws_size,
                              hipStream_t stream) {
  const float* x      = (const float*)d_in[0];
  const float* Wa_w   = (const float*)d_in[1];
  const float* Wa_b   = (const float*)d_in[2];
  const float* lg     = (const float*)d_in[3];
  const float* WB_w   = (const float*)d_in[4];
  const float* WB_b   = (const float*)d_in[5];
  const float* WC_w   = (const float*)d_in[6];
  const float* WC_b   = (const float*)d_in[7];
  const float* D_skip = (const float*)d_in[8];
  const float* ln_w   = (const float*)d_in[9];
  const float* ln_b   = (const float*)d_in[10];
  float* out = (float*)d_out;
  char* ws = (char*)d_ws;

  // Workspace (lifetime-overlapped):
  //   [0, 131KB): stats f32x2 (dead after gemm1) | ah fp16 spectra (late, 8.45MB)
  //   [16.9MB, 25.4MB): uh fp16 (h_hat in place)
  //   [33.55MB, 34.60MB): Wab bf16 (dead after gemm1)
  //   [34.60MB, 35.13MB): WCb bf16 (whole run)
  //   [35.13MB, +16.8MB): au fp16 (dead after fft) | hb bf16 8.4MB (late)
  float2*    stats = (float2*)(ws + 0);
  ushort_t*  Wab = (ushort_t*)(ws + 33554432);
  ushort_t*  WCb = (ushort_t*)(ws + 34603008);
  _Float16*  au  = (_Float16*)(ws + 35127296);
  ushort_t*  hb  = (ushort_t*)(ws + 35127296);   // aliases au (dead by then)
  _Float16*  ah  = (_Float16*)(ws + 0);          // aliases stats (dead by then)
  _Float16*  uh  = (_Float16*)(ws + 16908288);

  stats_prep_kernel<<<4864, 256, 0, stream>>>(x, stats, Wa_w, WB_w, WC_w, Wab, WCb);
  gemm1_ln<<<1024, 256, 0, stream>>>(x, stats, ln_w, ln_b, Wab, au);
  fft_fwd<<<M_ / 8, 512, 0, stream>>>(au, Wa_b, WB_b, lg, ah, uh);
  scan_kernel<<<B_ * KB_, 512, 0, stream>>>(ah, uh);
  ifft_kernel<<<M_ / 8, 256, 0, stream>>>(uh, hb);
  gemm2_epi<<<1024, 256, 0, stream>>>(hb, WCb, out, WC_b, D_skip, x);
}

// Round 9
// 104.204 us; speedup vs baseline: 1.2496x; 1.2496x over previous
//
#include <hip/hip_runtime.h>

// CirculantSSMLayer on MI355X.
// Pipeline: LN(+weight-prep) -> bf16 MFMA GEMM (Wa|WB fused) -> packed real radix-4
//           FFT256 -> per-(b,k) scan over T -> packed inverse radix-4 FFT
//           -> bf16 MFMA GEMM + batched epilogue.
// R9: REVERT R8's LN-into-gemm1 fusion (reg-staged LN serialized between barriers:
//     62us, MfmaUtil 11% -- staging VALU was the critical path). Keep R8's gemm2_epi
//     (hoisted bias/dskip, batched xres). gemm1 back to gload16 A-staging.

typedef unsigned short ushort_t;
typedef short s16x8 __attribute__((ext_vector_type(8)));
typedef float f32x4 __attribute__((ext_vector_type(4)));
typedef _Float16 f16x8 __attribute__((ext_vector_type(8)));
typedef _Float16 f16x2 __attribute__((ext_vector_type(2)));

#define B_ 4
#define T_ 4096
#define D_ 1024
#define N_ 256
#define KB_ 129
#define M_ (B_*T_)

// LDS bank swizzle for float2 arrays: XOR bits 4-5 into bits 1-2 (involution).
#define SWZ(i) ((i) ^ (((i) >> 3) & 6))
// base-4 digit reversal of an 8-bit index (radix-4 FFT input scramble)
#define DR4(n) ((((n) & 3) << 6) | (((n) & 12) << 2) | (((n) & 48) >> 2) | (((n) >> 6) & 3))

__device__ __forceinline__ ushort_t f2bf(float f) {
  unsigned u = __float_as_uint(f);
  u = (u + 0x7FFFu + ((u >> 16) & 1u)) >> 16;
  return (ushort_t)u;
}
__device__ __forceinline__ float2 cmul(float2 a, float2 b) {
  return make_float2(a.x*b.x - a.y*b.y, a.x*b.y + a.y*b.x);
}
__device__ __forceinline__ float fast_tanh(float x) {
  return 1.f - 2.f / (__expf(2.f * x) + 1.f);
}

typedef const __attribute__((address_space(1))) unsigned glb_u32;
typedef __attribute__((address_space(3))) unsigned lds_u32;
__device__ __forceinline__ void gload16(const void* g, void* l) {
  __builtin_amdgcn_global_load_lds((glb_u32*)g, (lds_u32*)l, 16, 0, 0);
}

// ---------------- layernorm (blocks 0..4095) + weight f32->bf16 (blocks 4096..4863) ----
__global__ __launch_bounds__(256) void ln_prep_kernel(const float* __restrict__ x,
    const float* __restrict__ w, const float* __restrict__ bb,
    ushort_t* __restrict__ xn,
    const float* __restrict__ Wa, const float* __restrict__ WB,
    const float* __restrict__ WC, ushort_t* __restrict__ Wab,
    ushort_t* __restrict__ WCb) {
  int tid = threadIdx.x;
  if (blockIdx.x >= 4096) {
    int i4 = ((blockIdx.x - 4096) * 256 + tid) * 4;
    float4 v;
    ushort_t* dst;
    if (i4 < 262144)        { v = *(const float4*)(Wa + i4);          dst = Wab + i4; }
    else if (i4 < 524288)   { v = *(const float4*)(WB + i4 - 262144); dst = Wab + i4; }
    else                    { v = *(const float4*)(WC + i4 - 524288); dst = WCb + i4 - 524288; }
    ushort4 o;
    o.x = f2bf(v.x); o.y = f2bf(v.y); o.z = f2bf(v.z); o.w = f2bf(v.w);
    *(ushort4*)dst = o;
    return;
  }
  int lane = tid & 63, wv = tid >> 6;
  int row = blockIdx.x * 4 + wv;
  const float4* xr = (const float4*)(x + (size_t)row * D_);
  float4 v[4];
  float s = 0.f, sq = 0.f;
  #pragma unroll
  for (int j = 0; j < 4; ++j) {
    v[j] = xr[lane + 64 * j];
    s  += v[j].x + v[j].y + v[j].z + v[j].w;
    sq += v[j].x*v[j].x + v[j].y*v[j].y + v[j].z*v[j].z + v[j].w*v[j].w;
  }
  #pragma unroll
  for (int off = 32; off >= 1; off >>= 1) {
    s  += __shfl_xor(s, off);
    sq += __shfl_xor(sq, off);
  }
  float mu  = s * (1.0f / D_);
  float var = sq * (1.0f / D_) - mu * mu;
  float rs  = rsqrtf(var + 1e-5f);
  const float4* w4 = (const float4*)w;
  const float4* b4 = (const float4*)bb;
  ushort4* o4 = (ushort4*)(xn + (size_t)row * D_);
  #pragma unroll
  for (int j = 0; j < 4; ++j) {
    float4 wv_ = w4[lane + 64 * j];
    float4 bv_ = b4[lane + 64 * j];
    ushort4 o;
    o.x = f2bf((v[j].x - mu) * rs * wv_.x + bv_.x);
    o.y = f2bf((v[j].y - mu) * rs * wv_.y + bv_.y);
    o.z = f2bf((v[j].z - mu) * rs * wv_.z + bv_.z);
    o.w = f2bf((v[j].w - mu) * rs * wv_.w + bv_.w);
    o4[lane + 64 * j] = o;
  }
}

// ---------------- gemm1: au[m][n] = sum_k xn[m][k]*Wab[n][k], fp16 out ----------------
// BM=128 x BN=64, BK=64, 4 waves (2x2), 16x16x32 MFMA, global_load_lds width-16,
// 2 barriers per K-step. LDS rows = 64 shorts (128B): granule-XOR swizzle,
// slot = gk ^ (row&7); staged via pre-swizzled per-lane GLOBAL source.
__global__ __launch_bounds__(256) void gemm1_k(
    const ushort_t* __restrict__ A, const ushort_t* __restrict__ B,
    _Float16* __restrict__ C) {
  constexpr int NF = 2;
  __shared__ ushort_t Alds[128 * 64];
  __shared__ ushort_t Blds[64 * 64];
  int bid = blockIdx.x;
  int cpx = gridDim.x >> 3;
  bid = (bid & 7) * cpx + (bid >> 3);
  int mt = bid >> 3, nt = bid & 7;
  int m0 = mt * 128, n0 = nt * 64;
  int tid = threadIdx.x;
  int lane = tid & 63, wid = tid >> 6;
  int wm = wid >> 1, wn = wid & 1;

  int lr8 = lane >> 3;
  int gd  = (lane & 7) ^ lr8;
  const ushort_t* gA = A + (size_t)(m0 + wid * 32 + lr8) * D_ + gd * 8;
  ushort_t* lA = &Alds[(wid * 32) * 64];
  const ushort_t* gB = B + (size_t)(n0 + wid * 16 + lr8) * D_ + gd * 8;
  ushort_t* lB = &Blds[(wid * 16) * 64];

  f32x4 acc[4][NF] = {};
  int rbase = lane & 15;
  int rb7 = lane & 7;
  int gk0 = lane >> 4;

  for (int k0 = 0; k0 < D_; k0 += 64) {
    __syncthreads();
    #pragma unroll
    for (int c = 0; c < 4; ++c)
      gload16(gA + (size_t)(c * 8) * D_ + k0, lA + c * 8 * 64);
    #pragma unroll
    for (int c = 0; c < 2; ++c)
      gload16(gB + (size_t)(c * 8) * D_ + k0, lB + c * 8 * 64);
    __syncthreads();
    #pragma unroll
    for (int kk = 0; kk < 2; ++kk) {
      int sl = ((gk0 + kk * 4) ^ rb7) * 8;
      s16x8 af[4], bf[NF];
      #pragma unroll
      for (int i = 0; i < 4; ++i)
        af[i] = *reinterpret_cast<const s16x8*>(&Alds[(wm * 64 + i * 16 + rbase) * 64 + sl]);
      #pragma unroll
      for (int j = 0; j < NF; ++j)
        bf[j] = *reinterpret_cast<const s16x8*>(&Blds[(wn * 32 + j * 16 + rbase) * 64 + sl]);
      #pragma unroll
      for (int i = 0; i < 4; ++i)
        #pragma unroll
        for (int j = 0; j < NF; ++j)
          acc[i][j] = __builtin_amdgcn_mfma_f32_16x16x32_bf16(af[i], bf[j], acc[i][j], 0, 0, 0);
    }
  }

  int r0 = (lane >> 4) * 4, cc = lane & 15;
  #pragma unroll
  for (int i = 0; i < 4; ++i)
    #pragma unroll
    for (int j = 0; j < NF; ++j) {
      int col = n0 + wn * 32 + j * 16 + cc;
      #pragma unroll
      for (int r = 0; r < 4; ++r) {
        int row = m0 + wm * 64 + i * 16 + r0 + r;
        C[(size_t)row * 512 + col] = (_Float16)acc[i][j][r];
      }
    }
}

// ---------------- gemm2: out[m][n] = sum_k hb[m][k]*WCb[n][k] + bias + dskip*xres ---
// BM=128 x BN=128, BK=64, 4 waves (2x2), gload16 both operands, granule swizzle,
// batched-epilogue (hoisted bias/dskip, 16 xres loads issued before use).
__global__ __launch_bounds__(256) void gemm2_epi(
    const ushort_t* __restrict__ A, const ushort_t* __restrict__ B,
    float* __restrict__ C,
    const float* __restrict__ bias, const float* __restrict__ dskip,
    const float* __restrict__ xres) {
  constexpr int BN = 128, NF = 4;
  __shared__ ushort_t Alds[128 * 64];
  __shared__ ushort_t Blds[BN * 64];
  int bid = blockIdx.x;
  int cpx = gridDim.x >> 3;
  bid = (bid & 7) * cpx + (bid >> 3);
  int mt = bid >> 3, nt = bid & 7;
  int m0 = mt * 128, n0 = nt * BN;
  int tid = threadIdx.x;
  int lane = tid & 63, wid = tid >> 6;
  int wm = wid >> 1, wn = wid & 1;

  int lr8 = lane >> 3;
  int gd  = (lane & 7) ^ lr8;
  const ushort_t* gA = A + (size_t)(m0 + wid * 32 + lr8) * N_ + gd * 8;
  ushort_t* lA = &Alds[(wid * 32) * 64];
  const ushort_t* gB = B + (size_t)(n0 + wid * 32 + lr8) * N_ + gd * 8;
  ushort_t* lB = &Blds[(wid * 32) * 64];

  f32x4 acc[4][NF] = {};
  int rbase = lane & 15;
  int rb7 = lane & 7;
  int gk0 = lane >> 4;

  for (int k0 = 0; k0 < N_; k0 += 64) {
    __syncthreads();
    #pragma unroll
    for (int c = 0; c < 4; ++c) {
      gload16(gA + (size_t)(c * 8) * N_ + k0, lA + c * 8 * 64);
      gload16(gB + (size_t)(c * 8) * N_ + k0, lB + c * 8 * 64);
    }
    __syncthreads();
    #pragma unroll
    for (int kk = 0; kk < 2; ++kk) {
      int sl = ((gk0 + kk * 4) ^ rb7) * 8;
      s16x8 af[4], bf[NF];
      #pragma unroll
      for (int i = 0; i < 4; ++i)
        af[i] = *reinterpret_cast<const s16x8*>(&Alds[(wm * 64 + i * 16 + rbase) * 64 + sl]);
      #pragma unroll
      for (int j = 0; j < NF; ++j)
        bf[j] = *reinterpret_cast<const s16x8*>(&Blds[(wn * 64 + j * 16 + rbase) * 64 + sl]);
      #pragma unroll
      for (int i = 0; i < 4; ++i)
        #pragma unroll
        for (int j = 0; j < NF; ++j)
          acc[i][j] = __builtin_amdgcn_mfma_f32_16x16x32_bf16(af[i], bf[j], acc[i][j], 0, 0, 0);
    }
  }

  int r0 = (lane >> 4) * 4, cc = lane & 15;
  float bcol[NF], dcol[NF];
  #pragma unroll
  for (int j = 0; j < NF; ++j) {
    int col = n0 + wn * 64 + j * 16 + cc;
    bcol[j] = bias[col];
    dcol[j] = dskip[col];
  }
  #pragma unroll
  for (int i = 0; i < 4; ++i) {
    float xr[NF][4];
    #pragma unroll
    for (int j = 0; j < NF; ++j)
      #pragma unroll
      for (int r = 0; r < 4; ++r)
        xr[j][r] = xres[(size_t)(m0 + wm * 64 + i * 16 + r0 + r) * D_ +
                        n0 + wn * 64 + j * 16 + cc];
    #pragma unroll
    for (int j = 0; j < NF; ++j) {
      int col = n0 + wn * 64 + j * 16 + cc;
      #pragma unroll
      for (int r = 0; r < 4; ++r) {
        int row = m0 + wm * 64 + i * 16 + r0 + r;
        C[(size_t)row * D_ + col] = acc[i][j][r] + bcol[j] + dcol[j] * xr[j][r];
      }
    }
  }
}

// ---------------- forward: bias+tanh+gate, packed radix-4 FFT256 ----------------
__global__ __launch_bounds__(512) void fft_fwd(const _Float16* __restrict__ au,
    const float* __restrict__ ba, const float* __restrict__ bu,
    const float* __restrict__ lg, _Float16* __restrict__ ah, _Float16* __restrict__ uh) {
  __shared__ float2 Z[8][256];
  __shared__ float2 Tw[256];
  int tid = threadIdx.x;
  int m0 = blockIdx.x * 8;
  int tg = tid >> 6, lane = tid & 63;
  if (tid < 256) {
    float sn, cs;
    __sincosf(-6.2831853071795864f / 256.f * (float)tid, &sn, &cs);
    Tw[tid] = make_float2(cs, sn);
  }
  float gamma = 1.f / (1.f + __expf(-lg[0]));
  const _Float16* row = au + (size_t)(m0 + tg) * (2 * N_);
  #pragma unroll
  for (int j = 0; j < 4; ++j) {
    int n = lane + 64 * j;
    float a = gamma * fast_tanh((float)row[n] + ba[n]);
    float u = (float)row[N_ + n] + bu[n];
    Z[tg][SWZ(DR4(n))] = make_float2(a, u);
  }
  __syncthreads();
  #pragma unroll
  for (int ls = 0; ls < 4; ++ls) {
    const int Q = 1 << (2 * ls);
    const int step = 64 >> (2 * ls);
    int j = lane & (Q - 1);
    int g = lane >> (2 * ls);
    int base = g * (4 * Q) + j;
    float2 a0 = Z[tg][SWZ(base)];
    float2 a1 = Z[tg][SWZ(base + Q)];
    float2 a2 = Z[tg][SWZ(base + 2 * Q)];
    float2 a3 = Z[tg][SWZ(base + 3 * Q)];
    if (ls > 0) {
      int e = j * step;
      a1 = cmul(a1, Tw[e]);
      a2 = cmul(a2, Tw[2 * e]);
      a3 = cmul(a3, Tw[3 * e]);
    }
    float2 t0 = make_float2(a0.x + a2.x, a0.y + a2.y);
    float2 t1 = make_float2(a0.x - a2.x, a0.y - a2.y);
    float2 t2 = make_float2(a1.x + a3.x, a1.y + a3.y);
    float2 d  = make_float2(a1.x - a3.x, a1.y - a3.y);
    float2 t3 = make_float2(d.y, -d.x);
    Z[tg][SWZ(base)]         = make_float2(t0.x + t2.x, t0.y + t2.y);
    Z[tg][SWZ(base + Q)]     = make_float2(t1.x + t3.x, t1.y + t3.y);
    Z[tg][SWZ(base + 2 * Q)] = make_float2(t0.x - t2.x, t0.y - t2.y);
    Z[tg][SWZ(base + 3 * Q)] = make_float2(t1.x - t3.x, t1.y - t3.y);
  }
  __syncthreads();
  int b = m0 >> 12, tb = m0 & (T_ - 1);
  #pragma unroll
  for (int p = 0; p < 3; ++p) {
    int k = (tid >> 3) + p * 64;
    int tl = tid & 7;
    if (k <= 128) {
      float2 zk = Z[tl][SWZ(k)];
      float2 zn = Z[tl][SWZ((256 - k) & 255)];
      float2 Af = make_float2(0.5f * (zk.x + zn.x), 0.5f * (zk.y - zn.y));
      float2 Uf = make_float2(0.5f * (zk.y + zn.y), -0.5f * (zk.x - zn.x));
      float mag = fmaxf(sqrtf(Af.x * Af.x + Af.y * Af.y), 1e-8f);
      float scl = 1.f / (1.f + __expf(-2.f * (1.f - mag)));
      Af.x *= scl; Af.y *= scl;
      size_t off2 = (((size_t)(b * KB_ + k)) * T_ + tb + tl) * 2;
      f16x2 av; av[0] = (_Float16)Af.x; av[1] = (_Float16)Af.y;
      f16x2 uv; uv[0] = (_Float16)Uf.x; uv[1] = (_Float16)Uf.y;
      *(f16x2*)(ah + off2) = av;
      *(f16x2*)(uh + off2) = uv;
    }
  }
}

// ---------------- time scan: h_t = a_t*h_{t-1} + u_t per (b,k) chain ----------------
__global__ __launch_bounds__(512) void scan_kernel(const _Float16* __restrict__ ah,
                                                   _Float16* __restrict__ uh) {
  __shared__ float4 wagg[8];
  int tid = threadIdx.x;
  int lane = tid & 63, wv = tid >> 6;
  size_t base = (size_t)blockIdx.x * T_ * 2;
  const f16x8* a8 = (const f16x8*)(ah + base);
  f16x8* u8 = (f16x8*)(uh + base);
  f16x8 Av[2], Uv[2];
  #pragma unroll
  for (int q = 0; q < 2; ++q) { Av[q] = a8[tid * 2 + q]; Uv[q] = u8[tid * 2 + q]; }
  float2 La[8], Lb[8];
  float2 ra = make_float2(1.f, 0.f), rb = make_float2(0.f, 0.f);
  #pragma unroll
  for (int e = 0; e < 8; ++e) {
    const int q = e >> 2, i = (e & 3) * 2;
    float2 a = make_float2((float)Av[q][i], (float)Av[q][i + 1]);
    float2 u = make_float2((float)Uv[q][i], (float)Uv[q][i + 1]);
    float2 t = cmul(a, rb);
    rb = make_float2(t.x + u.x, t.y + u.y);
    ra = cmul(ra, a);
    La[e] = ra; Lb[e] = rb;
  }
  #pragma unroll
  for (int off = 1; off < 64; off <<= 1) {
    float ax = __shfl_up(ra.x, off, 64), ay = __shfl_up(ra.y, off, 64);
    float bx = __shfl_up(rb.x, off, 64), by = __shfl_up(rb.y, off, 64);
    if (lane >= off) {
      float2 Ap = make_float2(ax, ay), Bp = make_float2(bx, by);
      float2 nB = cmul(ra, Bp);
      nB.x += rb.x; nB.y += rb.y;
      ra = cmul(Ap, ra);
      rb = nB;
    }
  }
  if (lane == 63) wagg[wv] = make_float4(ra.x, ra.y, rb.x, rb.y);
  __syncthreads();
  float2 Bw = make_float2(0.f, 0.f);
  for (int w0 = 0; w0 < wv; ++w0) {
    float4 g = wagg[w0];
    float2 gA = make_float2(g.x, g.y), gB = make_float2(g.z, g.w);
    Bw = cmul(gA, Bw);
    Bw.x += gB.x; Bw.y += gB.y;
  }
  float ax = __shfl_up(ra.x, 1, 64), ay = __shfl_up(ra.y, 1, 64);
  float bx = __shfl_up(rb.x, 1, 64), by = __shfl_up(rb.y, 1, 64);
  float2 Ae, Be;
  if (lane == 0) { Ae = make_float2(1.f, 0.f); Be = make_float2(0.f, 0.f); }
  else           { Ae = make_float2(ax, ay);   Be = make_float2(bx, by);   }
  float2 Pb = cmul(Ae, Bw);
  Pb.x += Be.x; Pb.y += Be.y;
  #pragma unroll
  for (int q = 0; q < 2; ++q) {
    f16x8 o;
    #pragma unroll
    for (int e2 = 0; e2 < 4; ++e2) {
      const int e = q * 4 + e2;
      float2 h = cmul(La[e], Pb);
      h.x += Lb[e].x; h.y += Lb[e].y;
      o[e2 * 2]     = (_Float16)h.x;
      o[e2 * 2 + 1] = (_Float16)h.y;
    }
    u8[tid * 2 + q] = o;
  }
}

// ---------------- inverse radix-4 FFT: 2 real rows per complex transform -> h bf16 ----
__global__ __launch_bounds__(256) void ifft_kernel(const _Float16* __restrict__ hh,
                                                   ushort_t* __restrict__ hb) {
  __shared__ float2 Hraw[8][132];
  __shared__ float2 Wz[4][256];
  __shared__ float2 Tw[256];
  int tid = threadIdx.x;
  int m0 = blockIdx.x * 8;
  int b = m0 >> 12, tb = m0 & (T_ - 1);
  {
    float sn, cs;
    __sincosf(6.2831853071795864f / 256.f * (float)tid, &sn, &cs);
    Tw[tid] = make_float2(cs, sn);
  }
  #pragma unroll
  for (int p = 0; p < 5; ++p) {
    int k = p * 32 + (tid >> 3), tl = tid & 7;
    if (k <= 128) {
      f16x2 hv = *(const f16x2*)(hh + (((size_t)(b * KB_ + k)) * T_ + tb + tl) * 2);
      Hraw[tl][k] = make_float2((float)hv[0], (float)hv[1]);
    }
  }
  __syncthreads();
  #pragma unroll
  for (int p = 0; p < 3; ++p) {
    int idx = p * 256 + tid;
    if (idx < 516) {
      int k = idx >> 2, pr = idx & 3;
      float2 h1 = Hraw[2 * pr][k], h2 = Hraw[2 * pr + 1][k];
      Wz[pr][SWZ(DR4(k))] = make_float2(h1.x - h2.y, h1.y + h2.x);
      if (k >= 1 && k <= 127)
        Wz[pr][SWZ(DR4(256 - k))] = make_float2(h1.x + h2.y, h2.x - h1.y);
    }
  }
  __syncthreads();
  int pr = tid >> 6, lane = tid & 63;
  #pragma unroll
  for (int ls = 0; ls < 4; ++ls) {
    const int Q = 1 << (2 * ls);
    const int step = 64 >> (2 * ls);
    int j = lane & (Q - 1);
    int g = lane >> (2 * ls);
    int base = g * (4 * Q) + j;
    float2 a0 = Wz[pr][SWZ(base)];
    float2 a1 = Wz[pr][SWZ(base + Q)];
    float2 a2 = Wz[pr][SWZ(base + 2 * Q)];
    float2 a3 = Wz[pr][SWZ(base + 3 * Q)];
    if (ls > 0) {
      int e = j * step;
      a1 = cmul(a1, Tw[e]);
      a2 = cmul(a2, Tw[2 * e]);
      a3 = cmul(a3, Tw[3 * e]);
    }
    float2 t0 = make_float2(a0.x + a2.x, a0.y + a2.y);
    float2 t1 = make_float2(a0.x - a2.x, a0.y - a2.y);
    float2 t2 = make_float2(a1.x + a3.x, a1.y + a3.y);
    float2 d  = make_float2(a1.x - a3.x, a1.y - a3.y);
    float2 t3 = make_float2(-d.y, d.x);
    Wz[pr][SWZ(base)]         = make_float2(t0.x + t2.x, t0.y + t2.y);
    Wz[pr][SWZ(base + Q)]     = make_float2(t1.x + t3.x, t1.y + t3.y);
    Wz[pr][SWZ(base + 2 * Q)] = make_float2(t0.x - t2.x, t0.y - t2.y);
    Wz[pr][SWZ(base + 3 * Q)] = make_float2(t1.x - t3.x, t1.y - t3.y);
  }
  const float inv = 1.f / 256.f;
  #pragma unroll
  for (int j = 0; j < 4; ++j) {
    int n = lane + 64 * j;
    float2 wv = Wz[pr][SWZ(n)];
    hb[(size_t)(m0 + 2 * pr) * N_ + n]     = f2bf(wv.x * inv);
    hb[(size_t)(m0 + 2 * pr + 1) * N_ + n] = f2bf(wv.y * inv);
  }
}

// ---------------- launch ----------------
extern "C" void kernel_launch(void* const* d_in, const int* in_sizes, int n_in,
                              void* d_out, int out_size, void* d_ws, size_t ws_size,
                              hipStream_t stream) {
  const float* x      = (const float*)d_in[0];
  const float* Wa_w   = (const float*)d_in[1];
  const float* Wa_b   = (const float*)d_in[2];
  const float* lg     = (const float*)d_in[3];
  const float* WB_w   = (const float*)d_in[4];
  const float* WB_b   = (const float*)d_in[5];
  const float* WC_w   = (const float*)d_in[6];
  const float* WC_b   = (const float*)d_in[7];
  const float* D_skip = (const float*)d_in[8];
  const float* ln_w   = (const float*)d_in[9];
  const float* ln_b   = (const float*)d_in[10];
  float* out = (float*)d_out;
  char* ws = (char*)d_ws;

  // Workspace (lifetime-overlapped):
  //   [0, 33.55MB): xn bf16 (early) | ah fp16 spectra 8.45MB + uh fp16 at 16.9MB (late)
  //   [33.55MB, 34.60MB): Wab bf16 (dead after gemm1)
  //   [34.60MB, 35.13MB): WCb bf16 (whole run)
  //   [35.13MB, +16.8MB): au fp16 (dead after fft) | hb bf16 8.4MB (late)
  ushort_t*  xn  = (ushort_t*)(ws + 0);
  ushort_t*  Wab = (ushort_t*)(ws + 33554432);
  ushort_t*  WCb = (ushort_t*)(ws + 34603008);
  _Float16*  au  = (_Float16*)(ws + 35127296);
  ushort_t*  hb  = (ushort_t*)(ws + 35127296);   // aliases au (dead by then)
  _Float16*  ah  = (_Float16*)(ws + 0);          // aliases xn (dead by then)
  _Float16*  uh  = (_Float16*)(ws + 16908288);   // h_hat written in place

  ln_prep_kernel<<<4864, 256, 0, stream>>>(x, ln_w, ln_b, xn,
                                           Wa_w, WB_w, WC_w, Wab, WCb);
  gemm1_k<<<1024, 256, 0, stream>>>(xn, Wab, au);
  fft_fwd<<<M_ / 8, 512, 0, stream>>>(au, Wa_b, WB_b, lg, ah, uh);
  scan_kernel<<<B_ * KB_, 512, 0, stream>>>(ah, uh);
  ifft_kernel<<<M_ / 8, 256, 0, stream>>>(uh, hb);
  gemm2_epi<<<1024, 256, 0, stream>>>(hb, WCb, out, WC_b, D_skip, x);
}